// Round 2
// baseline (229.892 us; speedup 1.0000x reference)
//
#include <hip/hip_runtime.h>
#include <stdint.h>

// Reference: pos += fl32(vel*dt); vel += fl32(fl32(-9.81)*fl32(0.01)); record pos.
// The np reference is the f32 scan — its rounding staircase drifts ~2% by n=1e7,
// so we emulate the f32 quantization exactly via piecewise-constant-increment runs.

static constexpr long long NSTEPS = 10000000LL;  // output rows
static constexpr long long NSTART = 131072LL;    // start of event emulation

struct Run { double pos; double inc; long long n0; };  // rows m>=n0: y = pos + (m-n0)*inc

// Actual f32 single-step pos increment (separate mul/add, no FMA contraction).
__device__ __forceinline__ double ai_inc(double pos, double vel, float dtf) {
    float p = (float)pos, v = (float)vel;
    float d  = __fmul_rn(v, dtf);
    float pn = __fadd_rn(p, d);
    return (double)pn - pos;
}
// Actual f32 single-step vel increment.
__device__ __forceinline__ double av_inc(double vel, float gdtf) {
    float v  = (float)vel;
    float vn = __fadd_rn(v, gdtf);
    return (double)vn - vel;
}

__global__ void prepass(const float* __restrict__ pos0, const float* __restrict__ vel0,
                        Run* __restrict__ runs, long long* __restrict__ count, long long cap) {
    if (threadIdx.x != 0 || blockIdx.x != 0) return;
    const float dtf  = 0.01f;
    const float gdtf = __fmul_rn(-9.81f, dtf);
    const double dtd = (double)dtf, gdtd = (double)gdtf;
    const double p0y = (double)pos0[1], v0y = (double)vel0[1];

    // Anchor at NSTART via exact-arithmetic closed form with f32-exact constants.
    const double nA  = (double)NSTART;
    double velA = v0y + nA * gdtd;
    double posA = p0y + dtd * (nA * v0y) + (dtd * gdtd) * (nA * (nA - 1.0) * 0.5);
    double pos = (double)(float)posA;   // snap to f32 grid
    double vel = (double)(float)velA;

    long long n = NSTART, cnt = 0;
    while (n < NSTEPS - 1 && cnt < cap) {
        const double inc = ai_inc(pos, vel, dtf);   // true f32 increment at current state
        const double cv  = av_inc(vel, gdtf);
        const long long rem = (NSTEPS - 1) - n;
        long long La = rem, Lb = rem, Lc = rem;

        if (inc != 0.0 && pos != 0.0) {             // pos binade exit
            int k; (void)frexp(pos, &k);            // |pos| in [2^(k-1), 2^k)
            double s = pos < 0.0 ? -1.0 : 1.0;
            double B = ((pos < 0.0) == (inc < 0.0)) ? ldexp(s, k) : ldexp(s, k - 1);
            double r = (B - pos) / inc;
            La = (r > 4.0e9) ? rem : ((long long)floor(r) - 1);
            if (La < 0) La = 0;
        }
        if (cv != 0.0 && vel != 0.0) {              // vel binade exit
            int k; (void)frexp(vel, &k);
            double s = vel < 0.0 ? -1.0 : 1.0;
            double B = ((vel < 0.0) == (cv < 0.0)) ? ldexp(s, k) : ldexp(s, k - 1);
            double r = (B - vel) / cv;
            Lb = (r > 4.0e9) ? rem : ((long long)floor(r) - 1);
            if (Lb < 0) Lb = 0;
        }
        if (cv != 0.0 && pos != 0.0) {              // delta crosses a rounding edge
            int k; (void)frexp(pos, &k);
            double ulp = ldexp(1.0, k - 24);
            double dd  = cv * dtd;
            double T   = inc + (dd < 0.0 ? -0.5 : 0.5) * ulp;
            double jx  = (T / dtd - vel) / cv;
            Lc = (jx > 4.0e9) ? rem : ((long long)floor(jx) + 2);  // slight over; shrink below
            if (Lc < 1) Lc = 1;
        }
        long long L = La < Lb ? La : Lb;
        if (Lc < L) L = Lc;
        if (rem < L) L = rem;
        if (L < 1) L = 1;

        int guard = 0;                              // endpoint-verify with real f32 ops
        while (L > 1) {
            double pe = pos + (double)(L - 1) * inc;
            double ve = vel + (double)(L - 1) * cv;
            if (ai_inc(pe, ve, dtf) == inc && av_inc(ve, gdtf) == cv) break;
            --L;
            if (++guard > 64) { L = 1; break; }
        }

        runs[cnt].pos = pos; runs[cnt].inc = inc; runs[cnt].n0 = n; ++cnt;
        pos += (double)L * inc;                     // exact: grid-aligned dyadics
        vel += (double)L * cv;
        n   += L;
    }
    *count = cnt;
}

__device__ __forceinline__ double eval_y(long long m, double p0y, double v0y,
                                         double dtd, double gdtd,
                                         const Run* __restrict__ runs, long long cnt) {
    if (m < NSTART) {
        double md = (double)m;
        return p0y + dtd * (md * v0y) + (dtd * gdtd) * (md * (md - 1.0) * 0.5);
    }
    long long lo = 0, hi = cnt - 1;
    while (lo < hi) {
        long long mid = (lo + hi + 1) >> 1;
        if (runs[mid].n0 <= m) lo = mid; else hi = mid - 1;
    }
    return runs[lo].pos + (double)(m - runs[lo].n0) * runs[lo].inc;
}

__global__ void fill(const float* __restrict__ pos0, const float* __restrict__ vel0,
                     const Run* __restrict__ runs, const long long* __restrict__ count,
                     float4* __restrict__ out, long long npairs) {
    const float dtf  = 0.01f;
    const float gdtf = __fmul_rn(-9.81f, dtf);
    const double dtd = (double)dtf, gdtd = (double)gdtf;
    const double p0x = (double)pos0[0], p0y = (double)pos0[1];
    const double v0y = (double)vel0[1];
    const double cx  = (double)__fmul_rn(vel0[0], dtf);  // constant f32 x-increment
    const long long cnt = *count;

    const long long stride = (long long)gridDim.x * blockDim.x;
    for (long long i = (long long)blockIdx.x * blockDim.x + threadIdx.x;
         i < npairs; i += stride) {
        const long long m0 = 2 * i, m1 = m0 + 1;
        float4 o;
        o.x = (float)(p0x + (double)m0 * cx);
        o.y = (float)eval_y(m0, p0y, v0y, dtd, gdtd, runs, cnt);
        o.z = (float)(p0x + (double)m1 * cx);
        o.w = (float)eval_y(m1, p0y, v0y, dtd, gdtd, runs, cnt);
        out[i] = o;
    }
}

extern "C" void kernel_launch(void* const* d_in, const int* in_sizes, int n_in,
                              void* d_out, int out_size, void* d_ws, size_t ws_size,
                              hipStream_t stream) {
    // Inputs: [0] ball_mass (unused), [1] initial_position[2], [2] initial_velocity[2].
    const float* pos0 = (const float*)d_in[1];
    const float* vel0 = (const float*)d_in[2];

    long long* cnt = (long long*)d_ws;
    Run* runs = (Run*)((char*)d_ws + 16);
    long long cap = ((long long)ws_size - 16) / (long long)sizeof(Run);
    if (cap > 16384) cap = 16384;
    if (cap < 1) cap = 1;

    prepass<<<1, 64, 0, stream>>>(pos0, vel0, runs, cnt, cap);

    const long long npairs = (long long)out_size / 4;  // 5,000,000 float4s
    fill<<<2048, 256, 0, stream>>>(pos0, vel0, runs, cnt, (float4*)d_out, npairs);
}

// Round 3
// 174.984 us; speedup vs baseline: 1.3138x; 1.3138x over previous
//
#include <hip/hip_runtime.h>
#include <stdint.h>

// Reference: pos += fl32(vel*dt); vel += fl32(fl32(-9.81)*fl32(0.01)); record pos.
// The np reference is the f32 scan; we emulate its rounding staircase exactly via
// piecewise-constant-increment runs. r2 passed (absmax 2.7e8 vs 1e9 thr); this
// round parallelizes the prepass endpoint-verify across the wave (193us -> ~30us).

static constexpr long long NSTEPS = 10000000LL;  // output rows
static constexpr long long NSTART = 131072LL;    // start of event emulation (even!)
static constexpr int LDSRUNS = 1024;             // LDS-cached run-table capacity

// Actual f32 single-step pos increment (separate mul/add, no FMA contraction).
__device__ __forceinline__ double ai_inc(double pos, double vel, float dtf) {
    float p = (float)pos, v = (float)vel;
    float d  = __fmul_rn(v, dtf);
    float pn = __fadd_rn(p, d);
    return (double)pn - pos;
}
// Actual f32 single-step vel increment.
__device__ __forceinline__ double av_inc(double vel, float gdtf) {
    float v  = (float)vel;
    float vn = __fadd_rn(v, gdtf);
    return (double)vn - vel;
}

__global__ __launch_bounds__(64) void prepass(
        const float* __restrict__ pos0, const float* __restrict__ vel0,
        long long* __restrict__ run_n0, double* __restrict__ run_pos,
        double* __restrict__ run_inc, long long* __restrict__ count, long long cap) {
    const int lane = threadIdx.x;  // single wave; state replicated wave-uniform
    const float dtf  = 0.01f;
    const float gdtf = __fmul_rn(-9.81f, dtf);
    const double dtd = (double)dtf, gdtd = (double)gdtf;
    const double p0y = (double)pos0[1], v0y = (double)vel0[1];

    // Anchor at NSTART via exact-arithmetic closed form, snapped to the f32 grid.
    const double nA  = (double)NSTART;
    double pos = (double)(float)(p0y + dtd * (nA * v0y) +
                                 (dtd * gdtd) * (nA * (nA - 1.0) * 0.5));
    double vel = (double)(float)(v0y + nA * gdtd);

    long long n = NSTART, cnt = 0;
    while (n < NSTEPS - 1 && cnt < cap) {
        const double inc = ai_inc(pos, vel, dtf);   // true f32 increments at current state
        const double cv  = av_inc(vel, gdtf);
        const long long rem = (NSTEPS - 1) - n;

        // Analytic upper-bound estimate for the run length (same as r2).
        long long La = rem, Lb = rem, Lc = rem;
        if (inc != 0.0 && pos != 0.0) {             // pos binade exit
            int k; (void)frexp(pos, &k);
            double s = pos < 0.0 ? -1.0 : 1.0;
            double B = ((pos < 0.0) == (inc < 0.0)) ? ldexp(s, k) : ldexp(s, k - 1);
            double r = (B - pos) / inc;
            La = (r > 4.0e9) ? rem : ((long long)r - 1);
            if (La < 0) La = 0;
        }
        if (cv != 0.0 && vel != 0.0) {              // vel binade exit
            int k; (void)frexp(vel, &k);
            double s = vel < 0.0 ? -1.0 : 1.0;
            double B = ((vel < 0.0) == (cv < 0.0)) ? ldexp(s, k) : ldexp(s, k - 1);
            double r = (B - vel) / cv;
            Lb = (r > 4.0e9) ? rem : ((long long)r - 1);
            if (Lb < 0) Lb = 0;
        }
        if (cv != 0.0 && pos != 0.0) {              // pos-increment rounding-edge crossing
            int k; (void)frexp(pos, &k);
            double ulp = ldexp(1.0, k - 24);
            double dd  = cv * dtd;
            double T   = inc + (dd < 0.0 ? -0.5 : 0.5) * ulp;
            double jx  = (T / dtd - vel) / cv;
            Lc = (jx > 4.0e9) ? rem : ((long long)jx + 2);
            if (Lc < 1) Lc = 1;
        }
        long long Lhi = La < Lb ? La : Lb;
        if (Lc < Lhi) Lhi = Lc;
        Lhi += 2;                                   // slack; downward search absorbs it
        if (Lhi > rem) Lhi = rem;
        if (Lhi < 1) Lhi = 1;

        // Wave-parallel endpoint verify: 64 candidates per round, highest valid wins.
        // Validity is (near-)monotone in L, so the highest set ballot bit is the run end.
        long long L = 1;
        long long base = Lhi;
        for (int round = 0; round < 16; ++round) {
            const long long candL = base - 63 + (long long)lane;
            bool valid = false;
            if (candL >= 1) {
                const double pe = pos + (double)(candL - 1) * inc;
                const double ve = vel + (double)(candL - 1) * cv;
                valid = (ai_inc(pe, ve, dtf) == inc) && (av_inc(ve, gdtf) == cv);
            }
            const unsigned long long m = __ballot(valid);
            if (m != 0ULL) { L = base - 63 + (long long)(63 - __clzll(m)); break; }
            base -= 64;
            if (base < 1) break;                    // L=1 fallback (always valid)
        }
        if (L < 1) L = 1;
        if (L > rem) L = rem;

        if (lane == 0) { run_n0[cnt] = n; run_pos[cnt] = pos; run_inc[cnt] = inc; }
        ++cnt;
        pos += (double)L * inc;                     // exact: grid-aligned dyadics
        vel += (double)L * cv;
        n   += L;
    }
    if (lane == 0) *count = cnt;
}

__device__ __forceinline__ double closed_y(long long m, double p0y, double v0y,
                                           double dtd, double gdtd) {
    double md = (double)m;
    return p0y + dtd * (md * v0y) + (dtd * gdtd) * (md * (md - 1.0) * 0.5);
}

__global__ __launch_bounds__(256) void fill(
        const float* __restrict__ pos0, const float* __restrict__ vel0,
        const long long* __restrict__ run_n0, const double* __restrict__ run_pos,
        const double* __restrict__ run_inc, const long long* __restrict__ count,
        float4* __restrict__ out, long long npairs) {
    __shared__ int    s_n0[LDSRUNS];
    __shared__ double s_pos[LDSRUNS];
    __shared__ double s_inc[LDSRUNS];

    const float dtf  = 0.01f;
    const float gdtf = __fmul_rn(-9.81f, dtf);
    const double dtd = (double)dtf, gdtd = (double)gdtf;
    const double p0x = (double)pos0[0], p0y = (double)pos0[1];
    const double v0y = (double)vel0[1];
    const double cx  = (double)__fmul_rn(vel0[0], dtf);  // constant f32 x-increment

    const int cnt = (int)*count;
    const bool lds_ok = (cnt > 0 && cnt <= LDSRUNS);
    if (lds_ok) {
        for (int i = threadIdx.x; i < cnt; i += blockDim.x) {
            s_n0[i]  = (int)run_n0[i];
            s_pos[i] = run_pos[i];
            s_inc[i] = run_inc[i];
        }
    }
    __syncthreads();

    const long long stride = (long long)gridDim.x * blockDim.x;
    for (long long i = (long long)blockIdx.x * blockDim.x + threadIdx.x;
         i < npairs; i += stride) {
        const long long m0 = 2 * i, m1 = m0 + 1;
        float4 o;
        o.x = (float)(p0x + (double)m0 * cx);
        o.z = (float)(p0x + (double)m1 * cx);

        if (m1 < NSTART) {  // NSTART even => m0,m1 on the same side
            o.y = (float)closed_y(m0, p0y, v0y, dtd, gdtd);
            o.w = (float)closed_y(m1, p0y, v0y, dtd, gdtd);
        } else if (lds_ok) {
            int lo = 0, hi = cnt - 1;
            const int t0 = (int)m0;
            while (lo < hi) {
                int mid = (lo + hi + 1) >> 1;
                if (s_n0[mid] <= t0) lo = mid; else hi = mid - 1;
            }
            o.y = (float)(s_pos[lo] + (double)(m0 - s_n0[lo]) * s_inc[lo]);
            const int r1 = (lo + 1 < cnt && s_n0[lo + 1] <= (int)m1) ? lo + 1 : lo;
            o.w = (float)(s_pos[r1] + (double)(m1 - s_n0[r1]) * s_inc[r1]);
        } else {            // fallback: search the global table
            long long lo = 0, hi = (long long)cnt - 1;
            while (lo < hi) {
                long long mid = (lo + hi + 1) >> 1;
                if (run_n0[mid] <= m0) lo = mid; else hi = mid - 1;
            }
            o.y = (float)(run_pos[lo] + (double)(m0 - run_n0[lo]) * run_inc[lo]);
            long long r1 = (lo + 1 < cnt && run_n0[lo + 1] <= m1) ? lo + 1 : lo;
            o.w = (float)(run_pos[r1] + (double)(m1 - run_n0[r1]) * run_inc[r1]);
        }
        out[i] = o;
    }
}

extern "C" void kernel_launch(void* const* d_in, const int* in_sizes, int n_in,
                              void* d_out, int out_size, void* d_ws, size_t ws_size,
                              hipStream_t stream) {
    // Inputs: [0] ball_mass (unused), [1] initial_position[2], [2] initial_velocity[2].
    const float* pos0 = (const float*)d_in[1];
    const float* vel0 = (const float*)d_in[2];

    long long cap = ((long long)ws_size - 64) / 24;  // 3 arrays of 8B each
    if (cap > 16384) cap = 16384;
    if (cap < 1) cap = 1;

    long long* cnt    = (long long*)d_ws;
    long long* rn0    = (long long*)((char*)d_ws + 64);
    double*    rpos   = (double*)((char*)d_ws + 64 + cap * 8);
    double*    rinc   = (double*)((char*)d_ws + 64 + cap * 16);

    prepass<<<1, 64, 0, stream>>>(pos0, vel0, rn0, rpos, rinc, cnt, cap);

    const long long npairs = (long long)out_size / 4;  // 5,000,000 float4s
    fill<<<2048, 256, 0, stream>>>(pos0, vel0, rn0, rpos, rinc, cnt,
                                   (float4*)d_out, npairs);
}